// Round 3
// baseline (308.717 us; speedup 1.0000x reference)
//
#include <hip/hip_runtime.h>
#include <hip/hip_bf16.h>

#define NN 100000
#define NE 1600000
#define INF 256
#define OUTF 128
#define NB ((NN + 255) / 256)     // 391
#define NBK ((NN + 127) / 128)    // 782 buckets of 128 nodes
#define CHUNK 8192
#define NBA ((NE + CHUNK - 1) / CHUNK)   // 196

typedef __attribute__((ext_vector_type(8))) short short8;
typedef __attribute__((ext_vector_type(4))) float f32x4;
typedef __attribute__((ext_vector_type(2))) float f32x2;

static __device__ __forceinline__ short f2bf(float f) {
    __hip_bfloat16 h = __float2bfloat16(f);
    return *reinterpret_cast<short*>(&h);
}

// ---------------------------------------------------------------------------
// Setup: zero deg + dsumI; block 0: wsv = W@a_src, wdv = W@a_dst;
// blocks 1..8: swizzled bf16 B fragments of W_em.
// Bsw layout: [kt(8)][ct(8)][lane(64)][j(8)]:
//   bf16(Wem[kt*32 + (lane>>4)*8 + j][ct*16 + (lane&15)])
// ---------------------------------------------------------------------------
__global__ void k_setup(const float* __restrict__ W, const float* __restrict__ a,
                        const float* __restrict__ Wem,
                        float* __restrict__ wsv, float* __restrict__ wdv,
                        ushort* __restrict__ Bsw, int* __restrict__ deg,
                        int* __restrict__ dsumI) {
    const int b = blockIdx.x, t = threadIdx.x;
    const int i = b * 256 + t;
    if (i < NN) { deg[i] = 0; dsumI[i] = 0; }
    if (b == 0) {
        const float* Wr = W + (size_t)t * OUTF;
        float sa = 0.f, sb = 0.f;
        #pragma unroll 8
        for (int k = 0; k < OUTF; ++k) {
            float w = Wr[k];
            sa += w * a[k];
            sb += w * a[OUTF + k];
        }
        wsv[t] = sa;
        wdv[t] = sb;
    } else if (b <= 8) {
        const int kt = b - 1;
        for (int idx = t; idx < 4096; idx += 256) {
            const int ct = idx >> 9;
            const int lane = (idx >> 3) & 63;
            const int j = idx & 7;
            const int k = kt * 32 + (lane >> 4) * 8 + j;
            const int c = ct * 16 + (lane & 15);
            Bsw[((size_t)(kt * 8 + ct) * 64 + lane) * 8 + j] =
                (ushort)f2bf(Wem[(size_t)k * OUTF + c]);
        }
    }
}

// ---------------------------------------------------------------------------
// MFMA matmul: hem(bf16) = x @ W_em; fused f32 s1 = x.ws, s2 = x.wd.
// C/D: col = lane&15, row = (lane>>4)*4 + reg   [m89/m91 verified mapping]
// hem stored SLICED for XCD-L2-resident gathers in k_aggregate:
//   hem[((ct*NN) + row)*16 + c16]  where feature = ct*16 + c16
//   -> slice ct is a contiguous 3.2 MB block (fits one XCD's 4 MiB L2).
// ---------------------------------------------------------------------------
__global__ __launch_bounds__(256) void k_mm(
    const float* __restrict__ x, const ushort* __restrict__ Bsw,
    const float* __restrict__ wsv, const float* __restrict__ wdv,
    float* __restrict__ s1, float* __restrict__ s2, ushort* __restrict__ hem) {
    const int t = threadIdx.x;
    const int w = t >> 6, lane = t & 63;
    const int br = blockIdx.x * 64 + w * 16;
    const int r0 = lane & 15, kq = lane >> 4;
    const int row = br + r0;
    const int rowc = (row < NN) ? row : NN - 1;
    const float* xp = x + (size_t)rowc * INF + kq * 8;
    const short8* bp = reinterpret_cast<const short8*>(Bsw);

    f32x4 acc[8];
    #pragma unroll
    for (int ct = 0; ct < 8; ++ct) acc[ct] = (f32x4){0.f, 0.f, 0.f, 0.f};
    float sa = 0.f, sb = 0.f;

    #pragma unroll
    for (int kt = 0; kt < 8; ++kt) {
        const float4 a0 = *reinterpret_cast<const float4*>(xp + kt * 32);
        const float4 a1 = *reinterpret_cast<const float4*>(xp + kt * 32 + 4);
        const float4 w0 = *reinterpret_cast<const float4*>(wsv + kt * 32 + kq * 8);
        const float4 w1 = *reinterpret_cast<const float4*>(wsv + kt * 32 + kq * 8 + 4);
        const float4 u0 = *reinterpret_cast<const float4*>(wdv + kt * 32 + kq * 8);
        const float4 u1 = *reinterpret_cast<const float4*>(wdv + kt * 32 + kq * 8 + 4);
        sa += a0.x * w0.x + a0.y * w0.y + a0.z * w0.z + a0.w * w0.w
            + a1.x * w1.x + a1.y * w1.y + a1.z * w1.z + a1.w * w1.w;
        sb += a0.x * u0.x + a0.y * u0.y + a0.z * u0.z + a0.w * u0.w
            + a1.x * u1.x + a1.y * u1.y + a1.z * u1.z + a1.w * u1.w;
        short8 af;
        af[0] = f2bf(a0.x); af[1] = f2bf(a0.y); af[2] = f2bf(a0.z); af[3] = f2bf(a0.w);
        af[4] = f2bf(a1.x); af[5] = f2bf(a1.y); af[6] = f2bf(a1.z); af[7] = f2bf(a1.w);
        #pragma unroll
        for (int ct = 0; ct < 8; ++ct) {
            const short8 bf = bp[(size_t)(kt * 8 + ct) * 64 + lane];
            acc[ct] = __builtin_amdgcn_mfma_f32_16x16x32_bf16(af, bf, acc[ct], 0, 0, 0);
        }
    }

    sa += __shfl_xor(sa, 16); sa += __shfl_xor(sa, 32);
    sb += __shfl_xor(sb, 16); sb += __shfl_xor(sb, 32);
    if (kq == 0 && row < NN) { s1[row] = sa; s2[row] = sb; }

    #pragma unroll
    for (int ct = 0; ct < 8; ++ct) {
        #pragma unroll
        for (int i = 0; i < 4; ++i) {
            const int rr = br + kq * 4 + i;
            if (rr < NN)
                hem[((size_t)ct * NN + rr) * 16 + r0] = (ushort)f2bf(acc[ct][i]);
        }
    }
}

// ---------------------------------------------------------------------------
// Degree histogram only (ee compute moved into k_binA).
// ---------------------------------------------------------------------------
__global__ void k_deg(const int* __restrict__ src, int* __restrict__ deg) {
    const int e = blockIdx.x * 256 + threadIdx.x;
    if (e < NE) atomicAdd(&deg[src[e]], 1);
}

// ---------------------------------------------------------------------------
// 3-level scan
// ---------------------------------------------------------------------------
__global__ void k_bsum(const int* __restrict__ deg, int* __restrict__ bsum) {
    __shared__ int sm[256];
    const int t = threadIdx.x;
    const int i = blockIdx.x * 256 + t;
    sm[t] = (i < NN) ? deg[i] : 0;
    __syncthreads();
    for (int off = 128; off > 0; off >>= 1) {
        if (t < off) sm[t] += sm[t + off];
        __syncthreads();
    }
    if (t == 0) bsum[blockIdx.x] = sm[0];
}

__global__ void k_bscan(const int* __restrict__ bsum, int* __restrict__ bpre) {
    __shared__ int sm[512];
    const int t = threadIdx.x;
    const int v = (t < NB) ? bsum[t] : 0;
    sm[t] = v;
    __syncthreads();
    for (int off = 1; off < 512; off <<= 1) {
        const int add = (t >= off) ? sm[t - off] : 0;
        __syncthreads();
        sm[t] += add;
        __syncthreads();
    }
    if (t < NB) bpre[t] = sm[t] - v;   // exclusive
}

// per-node exclusive offsets + sentinel offs[NN]=NE + bucket cursor init
__global__ void k_offs(const int* __restrict__ deg, const int* __restrict__ bpre,
                       int* __restrict__ offs, int* __restrict__ bcur) {
    __shared__ int sm[256];
    const int t = threadIdx.x;
    const int i = blockIdx.x * 256 + t;
    const int v = (i < NN) ? deg[i] : 0;
    sm[t] = v;
    __syncthreads();
    for (int off = 1; off < 256; off <<= 1) {
        const int add = (t >= off) ? sm[t - off] : 0;
        __syncthreads();
        sm[t] += add;
        __syncthreads();
    }
    const int excl = sm[t] - v + bpre[blockIdx.x];
    if (i < NN) {
        offs[i] = excl;
        if ((i & 127) == 0) bcur[i >> 7] = excl;
        if (i == NN - 1) offs[NN] = excl + v;
    }
}

// ---------------------------------------------------------------------------
// Pass A (fused with edge_e): compute ee = s1[s]+s2[d], write edge_e output,
// quantize v = exp(sigmoid(ee)) in (1,e) to 15-bit fixed point
// (vq = round((v-1)*16384), abs err <= 3e-5), accumulate per-node integer
// vq-sum (exact denominator), then bucket edges (bucket = src>>7) into
// contiguous per-bucket runs.  ebA record: { (dst<<7) | (src&127), vq }
// ---------------------------------------------------------------------------
__global__ __launch_bounds__(256) void k_binA(
    const int* __restrict__ src, const int* __restrict__ dst,
    const float* __restrict__ s1, const float* __restrict__ s2,
    float* __restrict__ ee_out, int* __restrict__ bcur,
    int2* __restrict__ ebA, int* __restrict__ dsumI) {
    __shared__ int cnt[NBK];
    __shared__ int base[NBK];
    const int t = threadIdx.x;
    const int e0 = blockIdx.x * CHUNK;

    for (int i = t; i < NBK; i += 256) cnt[i] = 0;
    __syncthreads();
    for (int i = t; i < CHUNK; i += 256) {
        const int e = e0 + i;
        if (e < NE) atomicAdd(&cnt[src[e] >> 7], 1);
    }
    __syncthreads();
    for (int i = t; i < NBK; i += 256) {
        const int c = cnt[i];
        base[i] = (c > 0) ? atomicAdd(&bcur[i], c) : 0;
    }
    __syncthreads();
    for (int i = t; i < NBK; i += 256) cnt[i] = 0;
    __syncthreads();
    for (int i = t; i < CHUNK; i += 256) {
        const int e = e0 + i;
        if (e < NE) {
            const int s = src[e], d = dst[e];
            const float ee = s1[s] + s2[d];
            ee_out[e] = ee;
            const float ob = 1.f / (1.f + __expf(-ee));
            const float v = __expf(ob);                   // in (1, e)
            int vq = (int)((v - 1.f) * 16384.f + 0.5f);   // <= 28147
            vq = (vq > 32767) ? 32767 : vq;
            atomicAdd(&dsumI[s], vq);                     // exact denom part
            const int bk = s >> 7;
            const int r = atomicAdd(&cnt[bk], 1);
            ebA[base[bk] + r] = make_int2((d << 7) | (s & 127), vq);
        }
    }
}

// ---------------------------------------------------------------------------
// Pass B: one block per bucket; LDS per-node cursors; scatter within the
// block-local CSR region.  Folds 1/denominator into the record:
//   denom*16384 = 16384*cnt + dsumI[node]   (exact integers)
//   att*32767   = (16384+vq) * 32767/(16384*cnt + dsumI)
// Record: (dst<<15) | attq, attq in [0,32767].
// ---------------------------------------------------------------------------
__global__ __launch_bounds__(256) void k_sortB(
    const int* __restrict__ offs, const int* __restrict__ deg,
    const int* __restrict__ dsumI, const int2* __restrict__ ebA,
    uint* __restrict__ ebB) {
    __shared__ int cur[128];
    __shared__ float fs[128];
    const int b = blockIdx.x, t = threadIdx.x;
    const int n0 = b << 7;
    const int lo = offs[n0];
    const int nhi = (n0 + 128 < NN) ? n0 + 128 : NN;
    const int hi = offs[nhi];
    if (t < 128) {
        const int node = n0 + t;
        if (node < NN) {
            cur[t] = offs[node] - lo;
            const int c = deg[node];
            fs[t] = (c > 0) ? 32767.f / (float)(c * 16384 + dsumI[node]) : 0.f;
        } else {
            cur[t] = 0;
            fs[t] = 0.f;
        }
    }
    __syncthreads();
    for (int i = lo + t; i < hi; i += 256) {
        const int2 r = ebA[i];
        const int sidx = r.x & 127;
        const uint d = ((unsigned)r.x) >> 7;
        float att = (float)(16384 + r.y) * fs[sidx];
        int attq = (int)(att + 0.5f);
        attq = (attq > 32767) ? 32767 : attq;
        const int p = atomicAdd(&cur[sidx], 1);
        ebB[lo + p] = (d << 15) | (uint)attq;
    }
}

// ---------------------------------------------------------------------------
// Aggregation, XCD-pinned feature-sliced (slice = blockIdx&7 -> fixed XCD,
// 3.2 MB hem slice stays L2-resident -- confirmed by FETCH 202->52 MB in R1).
// 2 lanes per (node, slice); each lane gathers uint4 = 8 bf16 features.
// Attention is pre-folded into the record (k_sortB), so the inner loop is:
//   load record -> and+cvt -> 16B gather -> 8 unpack + 8 FMA.
// Final scale 1/32767 applied once in the epilogue.
// ---------------------------------------------------------------------------
__global__ __launch_bounds__(256) void k_aggregate(
    const uint* __restrict__ eb, const int* __restrict__ offs,
    const int* __restrict__ deg, const ushort* __restrict__ hem,
    float* __restrict__ out0) {
    const int slice = blockIdx.x & 7;
    const int grp = blockIdx.x >> 3;          // 0..NBK-1, 128 nodes each
    const int t = threadIdx.x;
    const int node = grp * 128 + (t >> 1);
    if (node >= NN) return;
    const int f = t & 1;                       // which 16B half of the 32B row
    const char* hbase = reinterpret_cast<const char*>(hem)
                      + (size_t)slice * NN * 32 + f * 16;
    const int beg = offs[node];
    const int cnt = deg[node];

    float a0 = 0.f, a1 = 0.f, a2 = 0.f, a3 = 0.f;
    float a4 = 0.f, a5 = 0.f, a6 = 0.f, a7 = 0.f;

    int j = 0;
    for (; j + 4 <= cnt; j += 4) {
        const uint r0 = eb[beg + j];
        const uint r1 = eb[beg + j + 1];
        const uint r2 = eb[beg + j + 2];
        const uint r3 = eb[beg + j + 3];
        const float w0 = (float)(r0 & 0x7fffu);
        const float w1 = (float)(r1 & 0x7fffu);
        const float w2 = (float)(r2 & 0x7fffu);
        const float w3 = (float)(r3 & 0x7fffu);
        const uint4 u0 = *reinterpret_cast<const uint4*>(hbase + ((r0 & 0xffff8000u) >> 10));
        const uint4 u1 = *reinterpret_cast<const uint4*>(hbase + ((r1 & 0xffff8000u) >> 10));
        const uint4 u2 = *reinterpret_cast<const uint4*>(hbase + ((r2 & 0xffff8000u) >> 10));
        const uint4 u3 = *reinterpret_cast<const uint4*>(hbase + ((r3 & 0xffff8000u) >> 10));
        a0 += w0 * __uint_as_float(u0.x << 16) + w1 * __uint_as_float(u1.x << 16)
            + w2 * __uint_as_float(u2.x << 16) + w3 * __uint_as_float(u3.x << 16);
        a1 += w0 * __uint_as_float(u0.x & 0xffff0000u) + w1 * __uint_as_float(u1.x & 0xffff0000u)
            + w2 * __uint_as_float(u2.x & 0xffff0000u) + w3 * __uint_as_float(u3.x & 0xffff0000u);
        a2 += w0 * __uint_as_float(u0.y << 16) + w1 * __uint_as_float(u1.y << 16)
            + w2 * __uint_as_float(u2.y << 16) + w3 * __uint_as_float(u3.y << 16);
        a3 += w0 * __uint_as_float(u0.y & 0xffff0000u) + w1 * __uint_as_float(u1.y & 0xffff0000u)
            + w2 * __uint_as_float(u2.y & 0xffff0000u) + w3 * __uint_as_float(u3.y & 0xffff0000u);
        a4 += w0 * __uint_as_float(u0.z << 16) + w1 * __uint_as_float(u1.z << 16)
            + w2 * __uint_as_float(u2.z << 16) + w3 * __uint_as_float(u3.z << 16);
        a5 += w0 * __uint_as_float(u0.z & 0xffff0000u) + w1 * __uint_as_float(u1.z & 0xffff0000u)
            + w2 * __uint_as_float(u2.z & 0xffff0000u) + w3 * __uint_as_float(u3.z & 0xffff0000u);
        a6 += w0 * __uint_as_float(u0.w << 16) + w1 * __uint_as_float(u1.w << 16)
            + w2 * __uint_as_float(u2.w << 16) + w3 * __uint_as_float(u3.w << 16);
        a7 += w0 * __uint_as_float(u0.w & 0xffff0000u) + w1 * __uint_as_float(u1.w & 0xffff0000u)
            + w2 * __uint_as_float(u2.w & 0xffff0000u) + w3 * __uint_as_float(u3.w & 0xffff0000u);
    }
    for (; j < cnt; ++j) {
        const uint r0 = eb[beg + j];
        const float w0 = (float)(r0 & 0x7fffu);
        const uint4 u0 = *reinterpret_cast<const uint4*>(hbase + ((r0 & 0xffff8000u) >> 10));
        a0 += w0 * __uint_as_float(u0.x << 16);
        a1 += w0 * __uint_as_float(u0.x & 0xffff0000u);
        a2 += w0 * __uint_as_float(u0.y << 16);
        a3 += w0 * __uint_as_float(u0.y & 0xffff0000u);
        a4 += w0 * __uint_as_float(u0.z << 16);
        a5 += w0 * __uint_as_float(u0.z & 0xffff0000u);
        a6 += w0 * __uint_as_float(u0.w << 16);
        a7 += w0 * __uint_as_float(u0.w & 0xffff0000u);
    }
    const float s = 1.f / 32767.f;
    f32x4 o0, o1;
    o0[0] = a0 * s; o0[1] = a1 * s; o0[2] = a2 * s; o0[3] = a3 * s;
    o1[0] = a4 * s; o1[1] = a5 * s; o1[2] = a6 * s; o1[3] = a7 * s;
    float* op = out0 + (size_t)node * OUTF + slice * 16 + f * 8;
    __builtin_nontemporal_store(o0, reinterpret_cast<f32x4*>(op));
    __builtin_nontemporal_store(o1, reinterpret_cast<f32x4*>(op) + 1);
}

// ---------------------------------------------------------------------------
extern "C" void kernel_launch(void* const* d_in, const int* in_sizes, int n_in,
                              void* d_out, int out_size, void* d_ws, size_t ws_size,
                              hipStream_t stream) {
    const float* x   = (const float*)d_in[0];
    const int* eidx  = (const int*)d_in[1];
    const float* W   = (const float*)d_in[2];
    const float* a   = (const float*)d_in[3];
    const float* Wem = (const float*)d_in[4];

    const int* src = eidx;
    const int* dst = eidx + NE;

    float* out0 = (float*)d_out;            // h_prime: NN*128
    float* out1 = out0 + (size_t)NN * OUTF; // edge_e: NE

    // workspace layout (~47 MB), 16B-aligned chunks
    float* wsv   = (float*)d_ws;                     // 256
    float* wdv   = wsv + 256;                        // 256
    float* s1    = wdv + 256;                        // NN
    float* s2    = s1 + NN;                          // NN
    ushort* hem  = (ushort*)(s2 + NN);               // NN*128 bf16 (sliced layout)
    ushort* Bsw  = hem + (size_t)NN * OUTF;          // 32768
    int* deg     = (int*)(Bsw + 32768);              // NN
    int* offs    = deg + NN;                         // NN+4 (sentinel + pad)
    int* bsum    = offs + NN + 4;                    // 512
    int* bpre    = bsum + 512;                       // 512
    int* bcur    = bpre + 512;                       // 784 (NBK padded)
    int* dsumI   = bcur + 784;                       // NN
    int2* ebA    = (int2*)(dsumI + NN);              // NE * 8B
    uint* ebB    = (uint*)(ebA + NE);                // NE * 4B

    hipLaunchKernelGGL(k_setup, dim3(NB), dim3(256), 0, stream,
                       W, a, Wem, wsv, wdv, Bsw, deg, dsumI);
    hipLaunchKernelGGL(k_mm, dim3((NN + 63) / 64), dim3(256), 0, stream,
                       x, Bsw, wsv, wdv, s1, s2, hem);
    hipLaunchKernelGGL(k_deg, dim3((NE + 255) / 256), dim3(256), 0, stream,
                       src, deg);
    hipLaunchKernelGGL(k_bsum, dim3(NB), dim3(256), 0, stream, deg, bsum);
    hipLaunchKernelGGL(k_bscan, dim3(1), dim3(512), 0, stream, bsum, bpre);
    hipLaunchKernelGGL(k_offs, dim3(NB), dim3(256), 0, stream, deg, bpre, offs, bcur);
    hipLaunchKernelGGL(k_binA, dim3(NBA), dim3(256), 0, stream,
                       src, dst, s1, s2, out1, bcur, ebA, dsumI);
    hipLaunchKernelGGL(k_sortB, dim3(NBK), dim3(256), 0, stream,
                       offs, deg, dsumI, ebA, ebB);
    hipLaunchKernelGGL(k_aggregate, dim3(8 * NBK), dim3(256), 0, stream,
                       ebB, offs, deg, hem, out0);
}

// Round 4
// 195.985 us; speedup vs baseline: 1.5752x; 1.5752x over previous
//
#include <hip/hip_runtime.h>
#include <hip/hip_bf16.h>

#define NN 100000
#define NE 1600000
#define INF 256
#define OUTF 128
#define NBK ((NN + 127) / 128)           // 782 buckets of 128 nodes
#define CHUNK 4096
#define NBA ((NE + CHUNK - 1) / CHUNK)   // 391 chunks

typedef __attribute__((ext_vector_type(8))) short short8;
typedef __attribute__((ext_vector_type(4))) float f32x4;

static __device__ __forceinline__ short f2bf(float f) {
    __hip_bfloat16 h = __float2bfloat16(f);
    return *reinterpret_cast<short*>(&h);
}

// ---------------------------------------------------------------------------
// Setup: block 0: wsv = W@a_src, wdv = W@a_dst;
// blocks 1..8: swizzled bf16 B fragments of W_em.
// Bsw layout: [kt(8)][ct(8)][lane(64)][j(8)]:
//   bf16(Wem[kt*32 + (lane>>4)*8 + j][ct*16 + (lane&15)])
// ---------------------------------------------------------------------------
__global__ void k_setup(const float* __restrict__ W, const float* __restrict__ a,
                        const float* __restrict__ Wem,
                        float* __restrict__ wsv, float* __restrict__ wdv,
                        ushort* __restrict__ Bsw) {
    const int b = blockIdx.x, t = threadIdx.x;
    if (b == 0) {
        const float* Wr = W + (size_t)t * OUTF;
        float sa = 0.f, sb = 0.f;
        #pragma unroll 8
        for (int k = 0; k < OUTF; ++k) {
            float w = Wr[k];
            sa += w * a[k];
            sb += w * a[OUTF + k];
        }
        wsv[t] = sa;
        wdv[t] = sb;
    } else {
        const int kt = b - 1;
        for (int idx = t; idx < 4096; idx += 256) {
            const int ct = idx >> 9;
            const int lane = (idx >> 3) & 63;
            const int j = idx & 7;
            const int k = kt * 32 + (lane >> 4) * 8 + j;
            const int c = ct * 16 + (lane & 15);
            Bsw[((size_t)(kt * 8 + ct) * 64 + lane) * 8 + j] =
                (ushort)f2bf(Wem[(size_t)k * OUTF + c]);
        }
    }
}

// ---------------------------------------------------------------------------
// MFMA matmul: hem(bf16) = x @ W_em; fused f32 s1 = x.ws, s2 = x.wd.
// C/D: col = lane&15, row = (lane>>4)*4 + reg   [m89/m91 verified mapping]
// hem stored SLICED for XCD-L2-resident gathers in k_aggregate:
//   hem[((ct*NN) + row)*16 + c16] -> slice ct is a contiguous 3.2 MB block.
// ---------------------------------------------------------------------------
__global__ __launch_bounds__(256) void k_mm(
    const float* __restrict__ x, const ushort* __restrict__ Bsw,
    const float* __restrict__ wsv, const float* __restrict__ wdv,
    float* __restrict__ s1, float* __restrict__ s2, ushort* __restrict__ hem) {
    const int t = threadIdx.x;
    const int w = t >> 6, lane = t & 63;
    const int br = blockIdx.x * 64 + w * 16;
    const int r0 = lane & 15, kq = lane >> 4;
    const int row = br + r0;
    const int rowc = (row < NN) ? row : NN - 1;
    const float* xp = x + (size_t)rowc * INF + kq * 8;
    const short8* bp = reinterpret_cast<const short8*>(Bsw);

    f32x4 acc[8];
    #pragma unroll
    for (int ct = 0; ct < 8; ++ct) acc[ct] = (f32x4){0.f, 0.f, 0.f, 0.f};
    float sa = 0.f, sb = 0.f;

    #pragma unroll
    for (int kt = 0; kt < 8; ++kt) {
        const float4 a0 = *reinterpret_cast<const float4*>(xp + kt * 32);
        const float4 a1 = *reinterpret_cast<const float4*>(xp + kt * 32 + 4);
        const float4 w0 = *reinterpret_cast<const float4*>(wsv + kt * 32 + kq * 8);
        const float4 w1 = *reinterpret_cast<const float4*>(wsv + kt * 32 + kq * 8 + 4);
        const float4 u0 = *reinterpret_cast<const float4*>(wdv + kt * 32 + kq * 8);
        const float4 u1 = *reinterpret_cast<const float4*>(wdv + kt * 32 + kq * 8 + 4);
        sa += a0.x * w0.x + a0.y * w0.y + a0.z * w0.z + a0.w * w0.w
            + a1.x * w1.x + a1.y * w1.y + a1.z * w1.z + a1.w * w1.w;
        sb += a0.x * u0.x + a0.y * u0.y + a0.z * u0.z + a0.w * u0.w
            + a1.x * u1.x + a1.y * u1.y + a1.z * u1.z + a1.w * u1.w;
        short8 af;
        af[0] = f2bf(a0.x); af[1] = f2bf(a0.y); af[2] = f2bf(a0.z); af[3] = f2bf(a0.w);
        af[4] = f2bf(a1.x); af[5] = f2bf(a1.y); af[6] = f2bf(a1.z); af[7] = f2bf(a1.w);
        #pragma unroll
        for (int ct = 0; ct < 8; ++ct) {
            const short8 bf = bp[(size_t)(kt * 8 + ct) * 64 + lane];
            acc[ct] = __builtin_amdgcn_mfma_f32_16x16x32_bf16(af, bf, acc[ct], 0, 0, 0);
        }
    }

    sa += __shfl_xor(sa, 16); sa += __shfl_xor(sa, 32);
    sb += __shfl_xor(sb, 16); sb += __shfl_xor(sb, 32);
    if (kq == 0 && row < NN) { s1[row] = sa; s2[row] = sb; }

    #pragma unroll
    for (int ct = 0; ct < 8; ++ct) {
        #pragma unroll
        for (int i = 0; i < 4; ++i) {
            const int rr = br + kq * 4 + i;
            if (rr < NN)
                hem[((size_t)ct * NN + rr) * 16 + r0] = (ushort)f2bf(acc[ct][i]);
        }
    }
}

// ---------------------------------------------------------------------------
// Per-chunk per-bucket counts (LDS only, no global atomics).
// ---------------------------------------------------------------------------
__global__ __launch_bounds__(256) void k_cnt(
    const int* __restrict__ src, int* __restrict__ cntA) {
    __shared__ int cnt[NBK];
    const int t = threadIdx.x;
    const int c = blockIdx.x;
    const int e0 = c * CHUNK;
    for (int i = t; i < NBK; i += 256) cnt[i] = 0;
    __syncthreads();
    for (int i = t; i < CHUNK; i += 256) {
        const int e = e0 + i;
        if (e < NE) atomicAdd(&cnt[src[e] >> 7], 1);
    }
    __syncthreads();
    for (int i = t; i < NBK; i += 256) cntA[(size_t)c * NBK + i] = cnt[i];
}

// ---------------------------------------------------------------------------
// Per-bucket scan over chunks: baseA[c][b] = exclusive sum, bsumB[b] = total.
// One block per bucket, 512 threads (NBA=391 <= 512).
// ---------------------------------------------------------------------------
__global__ __launch_bounds__(512) void k_cscan(
    const int* __restrict__ cntA, int* __restrict__ baseA,
    int* __restrict__ bsumB) {
    __shared__ int sm[512];
    const int b = blockIdx.x;
    const int t = threadIdx.x;
    const int v = (t < NBA) ? cntA[(size_t)t * NBK + b] : 0;
    sm[t] = v;
    __syncthreads();
    for (int off = 1; off < 512; off <<= 1) {
        const int add = (t >= off) ? sm[t - off] : 0;
        __syncthreads();
        sm[t] += add;
        __syncthreads();
    }
    if (t < NBA) baseA[(size_t)t * NBK + b] = sm[t] - v;
    if (t == 511) bsumB[b] = sm[511];
}

// ---------------------------------------------------------------------------
// Bucket exclusive scan (1 block, 1024 threads, NBK=782) + sentinels.
// ---------------------------------------------------------------------------
__global__ __launch_bounds__(1024) void k_bbase(
    const int* __restrict__ bsumB, int* __restrict__ bbase,
    int* __restrict__ offs) {
    __shared__ int sm[1024];
    const int t = threadIdx.x;
    const int v = (t < NBK) ? bsumB[t] : 0;
    sm[t] = v;
    __syncthreads();
    for (int off = 1; off < 1024; off <<= 1) {
        const int add = (t >= off) ? sm[t - off] : 0;
        __syncthreads();
        sm[t] += add;
        __syncthreads();
    }
    if (t < NBK) bbase[t] = sm[t] - v;
    if (t == 0) { bbase[NBK] = NE; offs[NN] = NE; }
}

// ---------------------------------------------------------------------------
// Pass A (fused edge_e): single-pass deterministic scatter into bucket runs.
// ee = s1[s]+s2[d] -> edge_e output; v = exp(sigmoid(ee)) in (1,e) quantized
// to 15-bit fixed point vq = round((v-1)*16384), abs err <= 3e-5.
// Position = bbase[bk] + baseA[chunk][bk] + LDS running count. NO global atomics.
// ebA record: { (dst<<7) | (src&127), vq }
// ---------------------------------------------------------------------------
__global__ __launch_bounds__(256) void k_binA(
    const int* __restrict__ src, const int* __restrict__ dst,
    const float* __restrict__ s1, const float* __restrict__ s2,
    float* __restrict__ ee_out, const int* __restrict__ bbase,
    const int* __restrict__ baseA, int2* __restrict__ ebA) {
    __shared__ int base[NBK];
    __shared__ int cnt[NBK];
    const int t = threadIdx.x;
    const int c = blockIdx.x;
    const int e0 = c * CHUNK;
    for (int i = t; i < NBK; i += 256) {
        base[i] = bbase[i] + baseA[(size_t)c * NBK + i];
        cnt[i] = 0;
    }
    __syncthreads();
    for (int i = t; i < CHUNK; i += 256) {
        const int e = e0 + i;
        if (e < NE) {
            const int s = src[e], d = dst[e];
            const float ee = s1[s] + s2[d];
            ee_out[e] = ee;
            const float ob = 1.f / (1.f + __expf(-ee));
            const float v = __expf(ob);                   // in (1, e)
            int vq = (int)((v - 1.f) * 16384.f + 0.5f);   // <= 28147
            vq = (vq > 32767) ? 32767 : vq;
            const int bk = s >> 7;
            const int r = atomicAdd(&cnt[bk], 1);
            ebA[base[bk] + r] = make_int2((d << 7) | (s & 127), vq);
        }
    }
}

// ---------------------------------------------------------------------------
// Pass B: one block per bucket. Pass 1: LDS per-node count + vq-sum over the
// contiguous bucket run, 128-scan -> per-node CSR offsets (written to offs[])
// and folded 1/denominator. Pass 2: scatter 4-byte records (dst<<15)|attq,
//   denom*16384 = 16384*cnt + vqsum  (exact integers)
//   attq = round((16384+vq) * 32767 / denom16384), in [0,32767].
// ---------------------------------------------------------------------------
__global__ __launch_bounds__(256) void k_sortB(
    const int* __restrict__ bbase, const int2* __restrict__ ebA,
    uint* __restrict__ ebB, int* __restrict__ offs) {
    __shared__ int cnt[128];
    __shared__ int sum[128];
    __shared__ int sm[128];
    __shared__ int cur[128];
    __shared__ float fs[128];
    const int b = blockIdx.x, t = threadIdx.x;
    const int n0 = b << 7;
    const int lo = bbase[b];
    const int hi = bbase[b + 1];
    if (t < 128) { cnt[t] = 0; sum[t] = 0; }
    __syncthreads();
    for (int i = lo + t; i < hi; i += 256) {
        const int2 r = ebA[i];
        const int sidx = r.x & 127;
        atomicAdd(&cnt[sidx], 1);
        atomicAdd(&sum[sidx], r.y);
    }
    __syncthreads();
    const int v = (t < 128) ? cnt[t] : 0;
    if (t < 128) sm[t] = v;
    __syncthreads();
    for (int off = 1; off < 128; off <<= 1) {
        int add = 0;
        if (t < 128 && t >= off) add = sm[t - off];
        __syncthreads();
        if (t < 128) sm[t] += add;
        __syncthreads();
    }
    if (t < 128) {
        const int excl = sm[t] - v;
        cur[t] = excl;
        const int node = n0 + t;
        if (node < NN) offs[node] = lo + excl;
        fs[t] = (v > 0) ? 32767.f / (float)(v * 16384 + sum[t]) : 0.f;
    }
    __syncthreads();
    for (int i = lo + t; i < hi; i += 256) {
        const int2 r = ebA[i];
        const int sidx = r.x & 127;
        const uint d = ((unsigned)r.x) >> 7;
        const float att = (float)(16384 + r.y) * fs[sidx];
        int attq = (int)(att + 0.5f);
        attq = (attq > 32767) ? 32767 : attq;
        const int p = atomicAdd(&cur[sidx], 1);
        ebB[lo + p] = (d << 15) | (uint)attq;
    }
}

// ---------------------------------------------------------------------------
// Aggregation, XCD-pinned feature-sliced (slice = blockIdx&7 -> fixed XCD,
// 3.2 MB hem slice stays L2-resident -- confirmed FETCH 202->52 MB in R1).
// 2 lanes per (node, slice); each lane gathers uint4 = 8 bf16 features.
// Attention pre-folded into the record; degree from offs-diff.
// ---------------------------------------------------------------------------
__global__ __launch_bounds__(256) void k_aggregate(
    const uint* __restrict__ eb, const int* __restrict__ offs,
    const ushort* __restrict__ hem, float* __restrict__ out0) {
    const int slice = blockIdx.x & 7;
    const int grp = blockIdx.x >> 3;          // 0..NBK-1, 128 nodes each
    const int t = threadIdx.x;
    const int node = grp * 128 + (t >> 1);
    if (node >= NN) return;
    const int f = t & 1;                       // which 16B half of the 32B row
    const char* hbase = reinterpret_cast<const char*>(hem)
                      + (size_t)slice * NN * 32 + f * 16;
    const int beg = offs[node];
    const int cnt = offs[node + 1] - beg;

    float a0 = 0.f, a1 = 0.f, a2 = 0.f, a3 = 0.f;
    float a4 = 0.f, a5 = 0.f, a6 = 0.f, a7 = 0.f;

    int j = 0;
    for (; j + 4 <= cnt; j += 4) {
        const uint r0 = eb[beg + j];
        const uint r1 = eb[beg + j + 1];
        const uint r2 = eb[beg + j + 2];
        const uint r3 = eb[beg + j + 3];
        const float w0 = (float)(r0 & 0x7fffu);
        const float w1 = (float)(r1 & 0x7fffu);
        const float w2 = (float)(r2 & 0x7fffu);
        const float w3 = (float)(r3 & 0x7fffu);
        const uint4 u0 = *reinterpret_cast<const uint4*>(hbase + ((r0 & 0xffff8000u) >> 10));
        const uint4 u1 = *reinterpret_cast<const uint4*>(hbase + ((r1 & 0xffff8000u) >> 10));
        const uint4 u2 = *reinterpret_cast<const uint4*>(hbase + ((r2 & 0xffff8000u) >> 10));
        const uint4 u3 = *reinterpret_cast<const uint4*>(hbase + ((r3 & 0xffff8000u) >> 10));
        a0 += w0 * __uint_as_float(u0.x << 16) + w1 * __uint_as_float(u1.x << 16)
            + w2 * __uint_as_float(u2.x << 16) + w3 * __uint_as_float(u3.x << 16);
        a1 += w0 * __uint_as_float(u0.x & 0xffff0000u) + w1 * __uint_as_float(u1.x & 0xffff0000u)
            + w2 * __uint_as_float(u2.x & 0xffff0000u) + w3 * __uint_as_float(u3.x & 0xffff0000u);
        a2 += w0 * __uint_as_float(u0.y << 16) + w1 * __uint_as_float(u1.y << 16)
            + w2 * __uint_as_float(u2.y << 16) + w3 * __uint_as_float(u3.y << 16);
        a3 += w0 * __uint_as_float(u0.y & 0xffff0000u) + w1 * __uint_as_float(u1.y & 0xffff0000u)
            + w2 * __uint_as_float(u2.y & 0xffff0000u) + w3 * __uint_as_float(u3.y & 0xffff0000u);
        a4 += w0 * __uint_as_float(u0.z << 16) + w1 * __uint_as_float(u1.z << 16)
            + w2 * __uint_as_float(u2.z << 16) + w3 * __uint_as_float(u3.z << 16);
        a5 += w0 * __uint_as_float(u0.z & 0xffff0000u) + w1 * __uint_as_float(u1.z & 0xffff0000u)
            + w2 * __uint_as_float(u2.z & 0xffff0000u) + w3 * __uint_as_float(u3.z & 0xffff0000u);
        a6 += w0 * __uint_as_float(u0.w << 16) + w1 * __uint_as_float(u1.w << 16)
            + w2 * __uint_as_float(u2.w << 16) + w3 * __uint_as_float(u3.w << 16);
        a7 += w0 * __uint_as_float(u0.w & 0xffff0000u) + w1 * __uint_as_float(u1.w & 0xffff0000u)
            + w2 * __uint_as_float(u2.w & 0xffff0000u) + w3 * __uint_as_float(u3.w & 0xffff0000u);
    }
    for (; j < cnt; ++j) {
        const uint r0 = eb[beg + j];
        const float w0 = (float)(r0 & 0x7fffu);
        const uint4 u0 = *reinterpret_cast<const uint4*>(hbase + ((r0 & 0xffff8000u) >> 10));
        a0 += w0 * __uint_as_float(u0.x << 16);
        a1 += w0 * __uint_as_float(u0.x & 0xffff0000u);
        a2 += w0 * __uint_as_float(u0.y << 16);
        a3 += w0 * __uint_as_float(u0.y & 0xffff0000u);
        a4 += w0 * __uint_as_float(u0.z << 16);
        a5 += w0 * __uint_as_float(u0.z & 0xffff0000u);
        a6 += w0 * __uint_as_float(u0.w << 16);
        a7 += w0 * __uint_as_float(u0.w & 0xffff0000u);
    }
    const float s = 1.f / 32767.f;
    f32x4 o0, o1;
    o0[0] = a0 * s; o0[1] = a1 * s; o0[2] = a2 * s; o0[3] = a3 * s;
    o1[0] = a4 * s; o1[1] = a5 * s; o1[2] = a6 * s; o1[3] = a7 * s;
    float* op = out0 + (size_t)node * OUTF + slice * 16 + f * 8;
    __builtin_nontemporal_store(o0, reinterpret_cast<f32x4*>(op));
    __builtin_nontemporal_store(o1, reinterpret_cast<f32x4*>(op) + 1);
}

// ---------------------------------------------------------------------------
extern "C" void kernel_launch(void* const* d_in, const int* in_sizes, int n_in,
                              void* d_out, int out_size, void* d_ws, size_t ws_size,
                              hipStream_t stream) {
    const float* x   = (const float*)d_in[0];
    const int* eidx  = (const int*)d_in[1];
    const float* W   = (const float*)d_in[2];
    const float* a   = (const float*)d_in[3];
    const float* Wem = (const float*)d_in[4];

    const int* src = eidx;
    const int* dst = eidx + NE;

    float* out0 = (float*)d_out;            // h_prime: NN*128
    float* out1 = out0 + (size_t)NN * OUTF; // edge_e: NE

    // workspace layout (~36 MB), 16B-aligned chunks
    float* wsv   = (float*)d_ws;                     // 256
    float* wdv   = wsv + 256;                        // 256
    float* s1    = wdv + 256;                        // NN
    float* s2    = s1 + NN;                          // NN
    ushort* hem  = (ushort*)(s2 + NN);               // NN*128 bf16 (sliced layout)
    ushort* Bsw  = hem + (size_t)NN * OUTF;          // 32768
    int* offs    = (int*)(Bsw + 32768);              // NN+4 (sentinel + pad)
    int* bsumB   = offs + NN + 4;                    // NBK (pad to 784)
    int* bbase   = bsumB + 784;                      // NBK+1 (pad to 788)
    int* cntA    = bbase + 788;                      // NBA*NBK
    int* baseA   = cntA + NBA * NBK;                 // NBA*NBK
    int2* ebA    = (int2*)(baseA + NBA * NBK);       // NE * 8B
    uint* ebB    = (uint*)(ebA + NE);                // NE * 4B

    hipLaunchKernelGGL(k_setup, dim3(9), dim3(256), 0, stream,
                       W, a, Wem, wsv, wdv, Bsw);
    hipLaunchKernelGGL(k_mm, dim3((NN + 63) / 64), dim3(256), 0, stream,
                       x, Bsw, wsv, wdv, s1, s2, hem);
    hipLaunchKernelGGL(k_cnt, dim3(NBA), dim3(256), 0, stream, src, cntA);
    hipLaunchKernelGGL(k_cscan, dim3(NBK), dim3(512), 0, stream, cntA, baseA, bsumB);
    hipLaunchKernelGGL(k_bbase, dim3(1), dim3(1024), 0, stream, bsumB, bbase, offs);
    hipLaunchKernelGGL(k_binA, dim3(NBA), dim3(256), 0, stream,
                       src, dst, s1, s2, out1, bbase, baseA, ebA);
    hipLaunchKernelGGL(k_sortB, dim3(NBK), dim3(256), 0, stream,
                       bbase, ebA, ebB, offs);
    hipLaunchKernelGGL(k_aggregate, dim3(8 * NBK), dim3(256), 0, stream,
                       ebB, offs, hem, out0);
}